// Round 2
// baseline (135.473 us; speedup 1.0000x reference)
//
#include <hip/hip_runtime.h>

// VQ quantizer: N=131072 rows, K=1024 codes, D=10, fp32.
// R2: occupancy fix. 512 blocks x 512 threads (8 waves). Each block owns 256
// rows; all 8 waves process the SAME 256 rows (4 rows/lane) but each wave
// scans a different 1/8 of the codebook (k-split), then argmax-merge in LDS.
// 60KB LDS -> 2 blocks/CU -> 16 waves/CU = 4 waves/SIMD (was 1/SIMD in R1).
// Score = x.e - ||e||^2/2 (maximize) == argmin of squared distance.
// E staged in LDS at stride 12 floats (48B, 16B-aligned rows); slot [10]
// holds -0.5*||e||^2 as the accumulator init.

constexpr int N = 131072;
constexpr int K = 1024;
constexpr int D = 10;
constexpr int THREADS = 512;          // 8 waves
constexpr int BLOCKS = 512;           // 2 blocks/CU
constexpr int ROWS_PER_BLOCK = 256;   // N / BLOCKS
constexpr int ROWS_PER_LANE = 4;      // 256 / 64
constexpr int KSPLIT = 8;             // one codebook eighth per wave
constexpr int KPW = K / KSPLIT;       // 128
constexpr int ESTRIDE = 12;           // floats per codebook row in LDS

__global__ __launch_bounds__(THREADS, 4) void vq_kernel(
    const float* __restrict__ x,
    const float* __restrict__ E,
    float* __restrict__ out,
    float* __restrict__ loss_out)
{
    __shared__ float sE[K * ESTRIDE];                        // 48 KB
    __shared__ float sScore[KSPLIT][ROWS_PER_BLOCK];         // 8 KB
    __shared__ unsigned short sIdx[KSPLIT][ROWS_PER_BLOCK];  // 4 KB  (total 60 KB)

    const int tid  = threadIdx.x;
    const int lane = tid & 63;
    const int wave = tid >> 6;
    const int rowBase = blockIdx.x * ROWS_PER_BLOCK;

    // ---- stage codebook into LDS (coalesced contiguous read) ----
    for (int i = tid; i < K * D; i += THREADS) {
        int k = i / D;
        int d = i - k * D;
        sE[k * ESTRIDE + d] = E[i];
    }
    __syncthreads();
    // precompute -0.5*||e||^2 into slot 10
    for (int k = tid; k < K; k += THREADS) {
        float s = 0.f;
        #pragma unroll
        for (int d = 0; d < D; ++d) {
            float e = sE[k * ESTRIDE + d];
            s = fmaf(e, e, s);
        }
        sE[k * ESTRIDE + D] = -0.5f * s;
    }
    __syncthreads();

    // ---- load this lane's 4 rows of x into registers ----
    float xr[ROWS_PER_LANE][D];
    #pragma unroll
    for (int j = 0; j < ROWS_PER_LANE; ++j) {
        const float* xp = x + (size_t)(rowBase + lane + 64 * j) * D;
        #pragma unroll
        for (int d = 0; d < D; d += 2) {   // rows are 40B apart -> 8B aligned
            float2 v = *reinterpret_cast<const float2*>(xp + d);
            xr[j][d]     = v.x;
            xr[j][d + 1] = v.y;
        }
    }

    // ---- hot loop: this wave's eighth of the codebook ----
    float best[ROWS_PER_LANE];
    int   bidx[ROWS_PER_LANE];
    #pragma unroll
    for (int j = 0; j < ROWS_PER_LANE; ++j) { best[j] = -3.0e38f; bidx[j] = 0; }

    const int k0 = wave * KPW;
    #pragma unroll 2
    for (int kk = 0; kk < KPW; ++kk) {
        const int k = k0 + kk;
        const float* er = &sE[k * ESTRIDE];
        // wave-uniform address -> LDS broadcast reads
        const float e0 = er[0], e1 = er[1], e2 = er[2], e3 = er[3], e4 = er[4];
        const float e5 = er[5], e6 = er[6], e7 = er[7], e8 = er[8], e9 = er[9];
        const float ms = er[10];   // -0.5*||e||^2
        #pragma unroll
        for (int j = 0; j < ROWS_PER_LANE; ++j) {
            float acc = ms;
            acc = fmaf(xr[j][0], e0, acc);
            acc = fmaf(xr[j][1], e1, acc);
            acc = fmaf(xr[j][2], e2, acc);
            acc = fmaf(xr[j][3], e3, acc);
            acc = fmaf(xr[j][4], e4, acc);
            acc = fmaf(xr[j][5], e5, acc);
            acc = fmaf(xr[j][6], e6, acc);
            acc = fmaf(xr[j][7], e7, acc);
            acc = fmaf(xr[j][8], e8, acc);
            acc = fmaf(xr[j][9], e9, acc);
            if (acc > best[j]) { best[j] = acc; bidx[j] = k; }  // strict > keeps first k
        }
    }

    // ---- publish per-wave winners ----
    #pragma unroll
    for (int j = 0; j < ROWS_PER_LANE; ++j) {
        int r = lane + 64 * j;                 // stride-4B across lanes: conflict-free
        sScore[wave][r] = best[j];
        sIdx[wave][r]   = (unsigned short)bidx[j];
    }
    __syncthreads();

    // ---- merge across waves + epilogue (first 256 threads, 1 row each) ----
    float lsum = 0.f;
    for (int r = tid; r < ROWS_PER_BLOCK; r += THREADS) {
        float bs = sScore[0][r];
        int   bi = sIdx[0][r];
        #pragma unroll
        for (int w = 1; w < KSPLIT; ++w) {
            float s  = sScore[w][r];
            int   i2 = sIdx[w][r];
            if (s > bs) { bs = s; bi = i2; }   // ascending wave order keeps lowest k on tie
        }
        const float* er = &sE[bi * ESTRIDE];
        const float* xp = x   + (size_t)(rowBase + r) * D;
        float*       op = out + (size_t)(rowBase + r) * D;
        #pragma unroll
        for (int d = 0; d < D; ++d) {
            float xv   = xp[d];                // L1/L2-hot reload
            float q    = er[d];
            float diff = xv - q;               // codebook loss uses x - quantized
            lsum = fmaf(diff, diff, lsum);
            op[d] = xv + (q - xv);             // literal straight-through expression
        }
    }

    // ---- loss reduction: wave shuffle -> one atomic per wave ----
    #pragma unroll
    for (int off = 32; off > 0; off >>= 1)
        lsum += __shfl_down(lsum, off, 64);
    if (lane == 0)
        atomicAdd(loss_out, lsum * (1.0f / ((float)N * (float)D)));
}

extern "C" void kernel_launch(void* const* d_in, const int* in_sizes, int n_in,
                              void* d_out, int out_size, void* d_ws, size_t ws_size,
                              hipStream_t stream) {
    const float* x = (const float*)d_in[0];   // encoder_embedding [N, D]
    const float* E = (const float*)d_in[1];   // embedding_weight  [K, D]
    float* out  = (float*)d_out;              // quantized_st [N*D] then loss [1]
    float* loss = out + (size_t)N * D;

    hipMemsetAsync(loss, 0, sizeof(float), stream);  // d_out is re-poisoned each call
    vq_kernel<<<dim3(BLOCKS), dim3(THREADS), 0, stream>>>(x, E, out, loss);
}

// Round 3
// 124.432 us; speedup vs baseline: 1.0887x; 1.0887x over previous
//
#include <hip/hip_runtime.h>

// VQ quantizer: N=131072 rows, K=1024 codes, D=10, fp32.
// R3: LDS-free hot loop. Codebook in VGPRs: each lane holds 8 codes
// (k = khalf*512 + c*64 + lane); waves pair up (khalf=0/1) to cover K=1024.
// x rows stream as wave-uniform broadcast loads (L1/L2-hot, 40B/row).
// Per row: 80 reg-only FMAs -> in-lane argmax (ascending c => smallest k on
// ties) -> 64-lane shuffle argmax on packed u64 {sortable score, ~k}
// (u64 max picks larger ~k = smaller k on score ties, matching argmin-first)
// -> one LDS atomicMax per row per wave. Epilogue gathers E rows from L2.
// Score = x.e - ||e||^2/2 (identical fmaf chain order to R1/R2: absmax 0.0).

constexpr int N = 131072;
constexpr int K = 1024;
constexpr int D = 10;
constexpr int THREADS = 256;        // 4 waves = 2 pairs per block
constexpr int BLOCKS = 2048;
constexpr int ROWS_PER_BLOCK = 64;  // N / BLOCKS
constexpr int ROWS_PER_PAIR = 32;
constexpr int CPL = 8;              // codes per lane; 64*8 = 512 = K/2 per wave

__global__ __launch_bounds__(THREADS, 4) void vq_kernel(
    const float* __restrict__ x,
    const float* __restrict__ E,
    float* __restrict__ out,
    float* __restrict__ loss_out)
{
    __shared__ unsigned long long sBest[ROWS_PER_BLOCK];   // 512 B only

    const int tid  = threadIdx.x;
    const int lane = tid & 63;
    const int wave = tid >> 6;
    const int pairId = wave >> 1;    // 0..1
    const int khalf  = wave & 1;     // 0..1
    const int blockRow = blockIdx.x * ROWS_PER_BLOCK;
    const int rowBase  = blockRow + pairId * ROWS_PER_PAIR;

    if (tid < ROWS_PER_BLOCK) sBest[tid] = 0ULL;  // all real packed values > 0

    // ---- load this lane's 8 codes into registers (coalesced: consecutive
    //      lanes = consecutive k = contiguous 40B rows) ----
    float ec[CPL][D];
    float ms[CPL];
    #pragma unroll
    for (int c = 0; c < CPL; ++c) {
        const int k = khalf * 512 + c * 64 + lane;
        const float* ep = E + (size_t)k * D;
        #pragma unroll
        for (int d = 0; d < D; d += 2) {        // rows 40B apart -> 8B aligned
            float2 v = *reinterpret_cast<const float2*>(ep + d);
            ec[c][d] = v.x; ec[c][d + 1] = v.y;
        }
        float s = 0.f;
        #pragma unroll
        for (int d = 0; d < D; ++d) s = fmaf(ec[c][d], ec[c][d], s);
        ms[c] = -0.5f * s;                      // same formula/order as R1/R2
    }
    __syncthreads();                            // sBest init visible before atomics

    // ---- hot loop: stream 32 rows, all compute from registers ----
    float xv[D], xn[D];
    {
        const float* xp = x + (size_t)rowBase * D;
        #pragma unroll
        for (int d = 0; d < D; d += 2) {
            float2 v = *reinterpret_cast<const float2*>(xp + d);
            xv[d] = v.x; xv[d + 1] = v.y;
        }
    }
    for (int r = 0; r < ROWS_PER_PAIR; ++r) {
        if (r + 1 < ROWS_PER_PAIR) {            // prefetch next row (uniform branch)
            const float* xp = x + (size_t)(rowBase + r + 1) * D;
            #pragma unroll
            for (int d = 0; d < D; d += 2) {
                float2 v = *reinterpret_cast<const float2*>(xp + d);
                xn[d] = v.x; xn[d + 1] = v.y;
            }
        }
        float best = -3.0e38f;
        int   bc   = 0;
        #pragma unroll
        for (int c = 0; c < CPL; ++c) {         // 8 independent FMA chains
            float acc = ms[c];
            #pragma unroll
            for (int d = 0; d < D; ++d) acc = fmaf(xv[d], ec[c][d], acc);
            if (acc > best) { best = acc; bc = c; }  // strict >, ascending c
        }
        // pack {sortable score bits : ~k} into u64
        unsigned int sb = __float_as_uint(best);
        sb ^= (sb >> 31) ? 0xFFFFFFFFu : 0x80000000u;   // monotone fp32->u32
        const unsigned int kwin = (unsigned)(khalf * 512 + bc * 64 + lane);
        unsigned long long p =
            ((unsigned long long)sb << 32) | (unsigned int)(~kwin);
        // 64-lane argmax butterfly (two 32-bit shuffles per round)
        #pragma unroll
        for (int off = 32; off > 0; off >>= 1) {
            unsigned int lo = (unsigned int)p;
            unsigned int hi = (unsigned int)(p >> 32);
            unsigned int qlo = __shfl_xor(lo, off, 64);
            unsigned int qhi = __shfl_xor(hi, off, 64);
            unsigned long long q = ((unsigned long long)qhi << 32) | qlo;
            p = (q > p) ? q : p;
        }
        if (lane == 0)
            atomicMax(&sBest[pairId * ROWS_PER_PAIR + r], p);
        #pragma unroll
        for (int d = 0; d < D; ++d) xv[d] = xn[d];
    }
    __syncthreads();

    // ---- epilogue: wave 0 (tid<64) handles one row each ----
    float lsum = 0.f;
    if (tid < ROWS_PER_BLOCK) {
        const unsigned long long p = sBest[tid];
        const int kwin = (int)(~(unsigned int)(p & 0xFFFFFFFFu)) & (K - 1);
        const float* ep = E   + (size_t)kwin * D;             // L1/L2-hot gather
        const float* xp = x   + (size_t)(blockRow + tid) * D;
        float*       op = out + (size_t)(blockRow + tid) * D;
        #pragma unroll
        for (int d = 0; d < D; d += 2) {
            float2 ev = *reinterpret_cast<const float2*>(ep + d);
            float2 xw = *reinterpret_cast<const float2*>(xp + d);
            float d0 = xw.x - ev.x;
            float d1 = xw.y - ev.y;
            lsum = fmaf(d0, d0, lsum);
            lsum = fmaf(d1, d1, lsum);
            float2 o;
            o.x = xw.x + (ev.x - xw.x);          // literal straight-through expr
            o.y = xw.y + (ev.y - xw.y);
            *reinterpret_cast<float2*>(op + d) = o;
        }
    }
    if (tid < 64) {                              // tid<64 <=> wave 0 exactly
        #pragma unroll
        for (int off = 32; off > 0; off >>= 1)
            lsum += __shfl_down(lsum, off, 64);
        if (tid == 0)
            atomicAdd(loss_out, lsum * (1.0f / ((float)N * (float)D)));
    }
}

extern "C" void kernel_launch(void* const* d_in, const int* in_sizes, int n_in,
                              void* d_out, int out_size, void* d_ws, size_t ws_size,
                              hipStream_t stream) {
    const float* x = (const float*)d_in[0];   // encoder_embedding [N, D]
    const float* E = (const float*)d_in[1];   // embedding_weight  [K, D]
    float* out  = (float*)d_out;              // quantized_st [N*D] then loss [1]
    float* loss = out + (size_t)N * D;

    hipMemsetAsync(loss, 0, sizeof(float), stream);  // d_out re-poisoned each call
    vq_kernel<<<dim3(BLOCKS), dim3(THREADS), 0, stream>>>(x, E, out, loss);
}